// Round 5
// baseline (16549.428 us; speedup 1.0000x reference)
//
#include <hip/hip_runtime.h>
#include <hip/hip_bf16.h>
#include <math.h>

// ---------------- problem constants ----------------
#define S_   512
#define B_   64
#define V_   50000
#define E_   400
#define EP_  416          // E padded to multiple of 32 for MFMA K-tiles
#define H_   1152
#define G4_  4608         // 4*H
#define SB_  (S_*B_)      // 32768
#define CH_  16           // timesteps per xg chunk
#define NCH_ (S_/CH_)     // 32 chunks
#define MCH_ (CH_*B_)     // 1024 rows per chunk GEMM
#define SZW_ ((size_t)G4_*H_)   // elements per recurrent weight matrix

typedef unsigned short ushort_t;
typedef __attribute__((ext_vector_type(8))) short bf16x8;
typedef __attribute__((ext_vector_type(4))) float f32x4;

#define MFMA(a,b,c) __builtin_amdgcn_mfma_f32_16x16x32_bf16((a),(b),(c),0,0,0)

__device__ __forceinline__ ushort_t f2bf(float v) {
    unsigned int u = __float_as_uint(v);
    unsigned int r = (u + 0x7FFFu + ((u >> 16) & 1u)) >> 16;   // RNE
    return (ushort_t)r;
}
__device__ __forceinline__ float bf2f(ushort_t h) {
    return __uint_as_float(((unsigned int)h) << 16);
}
__device__ __forceinline__ float sigm(float x) { return 1.f / (1.f + expf(-x)); }

// ---- async global->LDS stage of 16B per lane (wave-uniform LDS base) ----
#if defined(__has_builtin)
#if __has_builtin(__builtin_amdgcn_global_load_lds)
#define HAVE_GLL 1
#endif
#endif

typedef __attribute__((address_space(1))) const unsigned int gas_u32;
typedef __attribute__((address_space(3))) unsigned int las_u32;

__device__ __forceinline__ void stage16(const ushort_t* gsrc, ushort_t* lbase, int lane) {
#ifdef HAVE_GLL
    // HW writes LDS at lbase + lane*16B; global src is per-lane. (m97 pattern)
    __builtin_amdgcn_global_load_lds((gas_u32*)gsrc, (las_u32*)lbase, 16, 0, 0);
#else
    *(bf16x8*)(lbase + (size_t)lane * 8) = *(const bf16x8*)gsrc;
#endif
}

// ---------------- prep: split fp32 weights into (hi, lo) bf16, pad K ----------------
__global__ __launch_bounds__(256) void k_split_pad(
    const float* __restrict__ src, ushort_t* __restrict__ hi, ushort_t* __restrict__ lo,
    int N, int Ks, int Kd)
{
    size_t tot = (size_t)N * Kd;
    for (size_t i = (size_t)blockIdx.x * blockDim.x + threadIdx.x; i < tot;
         i += (size_t)gridDim.x * blockDim.x) {
        int r = (int)(i / Kd), c = (int)(i % Kd);
        float v = (c < Ks) ? src[(size_t)r * Ks + c] : 0.f;
        ushort_t h = f2bf(v);
        hi[i] = h;
        lo[i] = f2bf(v - bf2f(h));
    }
}

// ------------- per-chunk embedding gather + split + pad (PAD row -> 0) -------------
// tok points at this chunk's first token; output slot is [MCH_][EP_] hi/lo.
__global__ __launch_bounds__(256) void k_embed_chunk(
    const int* __restrict__ tok, const float* __restrict__ emb,
    ushort_t* __restrict__ hi, ushort_t* __restrict__ lo)
{
    size_t tot = (size_t)MCH_ * EP_;
    for (size_t i = (size_t)blockIdx.x * blockDim.x + threadIdx.x; i < tot;
         i += (size_t)gridDim.x * blockDim.x) {
        int r = (int)(i / EP_), e = (int)(i % EP_);
        int tk = tok[r];
        float v = 0.f;
        if (e < E_ && tk != 1) v = emb[(size_t)tk * E_ + e];
        ushort_t h = f2bf(v);
        hi[i] = h;
        lo[i] = f2bf(v - bf2f(h));
    }
}

// ------------- merged multi-layer xg GEMM: C[m,n] = sum_k A[m,k]*W[n,k] -------------
// blockIdx.z = layer slot (inactive slots return). m97 structure: global_load_lds
// width-16 into LINEAR [128][32] LDS planes, 2-barrier K-loop, split-bf16 3-term.
// 4 waves; wave w stages plane w; each wave computes one 64x64 output quadrant.
struct GemmLayer {
    const ushort_t* Ahi; const ushort_t* Alo;
    const ushort_t* Bhi; const ushort_t* Blo;
    float* C; int K; int active;
};
struct GemmArgs { GemmLayer L[3]; };

__global__ __launch_bounds__(256) void k_gemm_multi(GemmArgs ga)
{
    const GemmLayer P = ga.L[blockIdx.z];
    if (!P.active) return;
    const int K = P.K;

    __shared__ __align__(16) ushort_t As[2][128 * 32];
    __shared__ __align__(16) ushort_t Bs[2][128 * 32];

    const int tid  = threadIdx.x;
    const int lane = tid & 63, wave = tid >> 6;
    const int wr = wave >> 1, wc = wave & 1;
    const int m0 = blockIdx.x * 128, n0 = blockIdx.y * 128;

    const ushort_t* gplane = (wave == 0) ? P.Ahi : (wave == 1) ? P.Alo
                           : (wave == 2) ? P.Bhi : P.Blo;
    ushort_t* lplane = (wave == 0) ? As[0] : (wave == 1) ? As[1]
                      : (wave == 2) ? Bs[0] : Bs[1];
    const int prow0 = (wave < 2) ? m0 : n0;
    const int srow  = lane >> 2;          // row within a 16-row issue
    const int sk    = (lane & 3) * 8;     // k element offset (16B granules)
    const ushort_t* gbase = gplane + (size_t)(prow0 + srow) * K + sk;

    f32x4 acc[4][4];
#pragma unroll
    for (int i = 0; i < 4; i++)
#pragma unroll
        for (int j = 0; j < 4; j++) acc[i][j] = (f32x4){0.f, 0.f, 0.f, 0.f};

    const int fr = lane & 15, fk = (lane >> 4) * 8;

    for (int k0 = 0; k0 < K; k0 += 32) {
        __syncthreads();                       // prior tile's LDS reads complete
#pragma unroll
        for (int i = 0; i < 8; i++)            // 8 x 16 rows = 128 rows of this plane
            stage16(gbase + (size_t)(i * 16) * K + k0, lplane + i * 16 * 32, lane);
        asm volatile("s_waitcnt vmcnt(0)" ::: "memory");
        __syncthreads();                       // tile ready

        bf16x8 af[4][2], bq[4][2];
#pragma unroll
        for (int i = 0; i < 4; i++) {
            af[i][0] = *(const bf16x8*)&As[0][(wr * 64 + i * 16 + fr) * 32 + fk];
            af[i][1] = *(const bf16x8*)&As[1][(wr * 64 + i * 16 + fr) * 32 + fk];
            bq[i][0] = *(const bf16x8*)&Bs[0][(wc * 64 + i * 16 + fr) * 32 + fk];
            bq[i][1] = *(const bf16x8*)&Bs[1][(wc * 64 + i * 16 + fr) * 32 + fk];
        }
#pragma unroll
        for (int i = 0; i < 4; i++)
#pragma unroll
            for (int j = 0; j < 4; j++) {
                f32x4 a = acc[i][j];
                a = MFMA(af[i][0], bq[j][0], a);   // hi*hi
                a = MFMA(af[i][0], bq[j][1], a);   // hi*lo
                a = MFMA(af[i][1], bq[j][0], a);   // lo*hi
                acc[i][j] = a;
            }
    }

    const int fq = lane >> 4;
#pragma unroll
    for (int i = 0; i < 4; i++)
#pragma unroll
        for (int j = 0; j < 4; j++)
#pragma unroll
            for (int r = 0; r < 4; r++) {
                int row = m0 + wr * 64 + i * 16 + fq * 4 + r;
                int col = n0 + wc * 64 + j * 16 + fr;
                P.C[(size_t)row * G4_ + col] = acc[i][j][r];
            }
}

// ---------------- merged 3-layer LSTM step (wavefront pipeline) ----------------
// grid (72, 3): blockIdx.y = layer slot; block 256 = 4 waves.
// Wave w = K-quarter kq; each wave computes ALL 4 gates x ALL 4 batch-groups
// (acc[4][4]) for its 16-unit tile over K=288 -> W and h each read ONCE per block
// (issued L2 traffic per step: 216 x 590 KB = 127 MB vs 324 MB for the 16-wave
// gate-split layout). LDS reduction over kq; 256 consumer threads x 4 iters apply
// activations, update c, write fp32 h to d_out and split-bf16 h to y ring + state.
struct LayerStep {
    const ushort_t* hr;      // [2 planes: hi|lo][64][1152]
    ushort_t*       hw;
    const ushort_t* Whi; const ushort_t* Wlo;   // [4608][1152]
    const float*    xg;      // already offset to this step: [64][4608]
    const float*    bih; const float* bhh;      // [4608]
    float*          cbuf;    // [64][1152]
    float*          out_t;   // [64][1152] fp32 (d_out slab)
    ushort_t*       yhi; ushort_t* ylo;         // [64][1152] or null (layer 2)
    int t; int active;
};
struct StepArgs { LayerStep L[3]; };

__global__ __launch_bounds__(256) void k_step_merged(StepArgs sa) {
    const LayerStep P = sa.L[blockIdx.y];
    if (!P.active) return;

    const int tid = threadIdx.x, lane = tid & 63, kq = tid >> 6;  // wave = K-quarter
    const int u0 = blockIdx.x * 16;

    f32x4 acc[4][4];                             // [gate][batch-group]
#pragma unroll
    for (int g = 0; g < 4; g++)
#pragma unroll
        for (int m = 0; m < 4; m++) acc[g][m] = (f32x4){0.f, 0.f, 0.f, 0.f};

    if (P.t > 0) {
        const int fr = lane & 15, fk = (lane >> 4) * 8;
        const int kbase = kq * 288;              // 1152/4
        const ushort_t* ah[4]; const ushort_t* al[4];
#pragma unroll
        for (int m = 0; m < 4; m++) {
            ah[m] = P.hr + (size_t)(m * 16 + fr) * H_ + kbase + fk;
            al[m] = ah[m] + (size_t)B_ * H_;     // lo plane
        }
        const ushort_t* bh[4]; const ushort_t* bl[4];
#pragma unroll
        for (int g = 0; g < 4; g++) {
            const size_t brow = (size_t)(g * H_ + u0 + fr) * H_ + kbase + fk;
            bh[g] = P.Whi + brow;
            bl[g] = P.Wlo + brow;
        }
        for (int k0 = 0; k0 < 288; k0 += 32) {
            bf16x8 vbh[4], vbl[4], vah[4], val[4];
#pragma unroll
            for (int g = 0; g < 4; g++) {
                vbh[g] = *(const bf16x8*)(bh[g] + k0);
                vbl[g] = *(const bf16x8*)(bl[g] + k0);
            }
#pragma unroll
            for (int m = 0; m < 4; m++) {
                vah[m] = *(const bf16x8*)(ah[m] + k0);
                val[m] = *(const bf16x8*)(al[m] + k0);
            }
#pragma unroll
            for (int g = 0; g < 4; g++)
#pragma unroll
                for (int m = 0; m < 4; m++) {
                    f32x4 a = acc[g][m];
                    a = MFMA(vah[m], vbh[g], a);   // hi*hi
                    a = MFMA(vah[m], vbl[g], a);   // hi*lo
                    a = MFMA(val[m], vbh[g], a);   // lo*hi
                    acc[g][m] = a;
                }
        }
    }

    __shared__ float g_s[4][64][68];             // [kq][batch][gate*16+u], padded
    {
        const int fc = lane & 15;
        const int rb = (lane >> 4) * 4;
#pragma unroll
        for (int g = 0; g < 4; g++)
#pragma unroll
            for (int m = 0; m < 4; m++)
#pragma unroll
                for (int r = 0; r < 4; r++)
                    g_s[kq][m * 16 + rb + r][g * 16 + fc] = acc[g][m][r];
    }
    __syncthreads();

    // consumer: 256 threads x 4 iterations = 1024 (b,u) pairs
    for (int p = tid; p < 1024; p += 256) {
        const int u = p & 15, b = p >> 4;
        const int col = u0 + u;
        const float* xr = P.xg + (size_t)b * G4_;
        float gi = g_s[0][b][u]      + g_s[1][b][u]      + g_s[2][b][u]      + g_s[3][b][u]
                 + xr[col]           + P.bih[col]           + P.bhh[col];
        float gf = g_s[0][b][16+u]   + g_s[1][b][16+u]   + g_s[2][b][16+u]   + g_s[3][b][16+u]
                 + xr[H_ + col]      + P.bih[H_ + col]      + P.bhh[H_ + col];
        float gg = g_s[0][b][32+u]   + g_s[1][b][32+u]   + g_s[2][b][32+u]   + g_s[3][b][32+u]
                 + xr[2*H_ + col]    + P.bih[2*H_ + col]    + P.bhh[2*H_ + col];
        float go = g_s[0][b][48+u]   + g_s[1][b][48+u]   + g_s[2][b][48+u]   + g_s[3][b][48+u]
                 + xr[3*H_ + col]    + P.bih[3*H_ + col]    + P.bhh[3*H_ + col];
        float ig = sigm(gi), fg = sigm(gf), gc = tanhf(gg), og = sigm(go);
        size_t idx = (size_t)b * H_ + col;
        float cn = fg * P.cbuf[idx] + ig * gc;
        float hn = og * tanhf(cn);
        P.cbuf[idx]  = cn;
        P.out_t[idx] = hn;
        ushort_t hh = f2bf(hn);
        ushort_t hl = f2bf(hn - bf2f(hh));
        P.hw[idx] = hh;
        P.hw[(size_t)B_ * H_ + idx] = hl;
        if (P.yhi) { P.yhi[idx] = hh; P.ylo[idx] = hl; }
    }
}

// ---------------- host-side launcher ----------------
extern "C" void kernel_launch(void* const* d_in, const int* in_sizes, int n_in,
                              void* d_out, int out_size, void* d_ws, size_t ws_size,
                              hipStream_t stream)
{
    const int*   tokens = (const int*)d_in[0];
    const float* emb    = (const float*)d_in[1];
    const float* wih0   = (const float*)d_in[2];
    const float* whh0   = (const float*)d_in[3];
    const float* bih0   = (const float*)d_in[4];
    const float* bhh0   = (const float*)d_in[5];
    const float* wihr   = (const float*)d_in[6];
    const float* whhr   = (const float*)d_in[7];
    const float* bihr   = (const float*)d_in[8];
    const float* bhhr   = (const float*)d_in[9];
    float* out = (float*)d_out;
    (void)in_sizes; (void)n_in; (void)out_size; (void)ws_size;

    char* ws = (char*)d_ws;
    size_t o = 0;
    auto alloc = [&](size_t bytes) -> char* {
        char* p = ws + o;
        o = (o + bytes + 255) & ~(size_t)255;
        return p;
    };
    ushort_t* wih0_hi = (ushort_t*)alloc((size_t)G4_ * EP_ * 2);
    ushort_t* wih0_lo = (ushort_t*)alloc((size_t)G4_ * EP_ * 2);
    ushort_t* whh_hi  = (ushort_t*)alloc(3 * SZW_ * 2);
    ushort_t* whh_lo  = (ushort_t*)alloc(3 * SZW_ * 2);
    ushort_t* wihr_hi = (ushort_t*)alloc(2 * SZW_ * 2);
    ushort_t* wihr_lo = (ushort_t*)alloc(2 * SZW_ * 2);
    // single-slot split-x staging for the current layer-0 chunk
    ushort_t* xs_hi = (ushort_t*)alloc((size_t)MCH_ * EP_ * 2);
    ushort_t* xs_lo = (ushort_t*)alloc((size_t)MCH_ * EP_ * 2);
    // y ring: layers 0,1 only; 2 slots of one chunk each, hi & lo planes
    const size_t YCH = (size_t)MCH_ * H_;              // elements per slot
    ushort_t* yr_hi[2], * yr_lo[2];
    for (int l = 0; l < 2; ++l) {
        yr_hi[l] = (ushort_t*)alloc(2 * YCH * 2);
        yr_lo[l] = (ushort_t*)alloc(2 * YCH * 2);
    }
    float* xg[3];
    for (int l = 0; l < 3; ++l) xg[l] = (float*)alloc((size_t)MCH_ * G4_ * 4);
    const size_t HSTP = (size_t)2 * B_ * H_;           // elements per ping buffer
    ushort_t* hst[3];
    float* cbuf[3];
    for (int l = 0; l < 3; ++l) {
        hst[l]  = (ushort_t*)alloc(2 * HSTP * 2);
        cbuf[l] = (float*)alloc((size_t)B_ * H_ * 4);
    }

    // ---- prep (every call; ws is re-poisoned by the harness) ----
    k_split_pad<<<2048, 256, 0, stream>>>(wih0, wih0_hi, wih0_lo, G4_, E_, EP_);
    k_split_pad<<<2048, 256, 0, stream>>>(whh0, whh_hi, whh_lo, G4_, H_, H_);
    k_split_pad<<<2048, 256, 0, stream>>>(whhr, whh_hi + SZW_, whh_lo + SZW_, G4_, H_, H_);
    k_split_pad<<<2048, 256, 0, stream>>>(whhr + SZW_, whh_hi + 2 * SZW_, whh_lo + 2 * SZW_, G4_, H_, H_);
    k_split_pad<<<2048, 256, 0, stream>>>(wihr, wihr_hi, wihr_lo, G4_, H_, H_);
    k_split_pad<<<2048, 256, 0, stream>>>(wihr + SZW_, wihr_hi + SZW_, wihr_lo + SZW_, G4_, H_, H_);
    for (int l = 0; l < 3; ++l)
        hipMemsetAsync(cbuf[l], 0, (size_t)B_ * H_ * 4, stream);

    const float* bihA[3] = { bih0, bihr, bihr + G4_ };
    const float* bhhA[3] = { bhh0, bhhr, bhhr + G4_ };

    // ---- wavefront pipeline: phase p runs layer l on chunk c = p - l ----
    for (int p = 0; p < NCH_ + 2; ++p) {
        // (a) stage layer-0 chunk p embeddings (single slot; consumed this phase)
        if (p < NCH_)
            k_embed_chunk<<<832, 256, 0, stream>>>(tokens + (size_t)p * MCH_, emb, xs_hi, xs_lo);

        // (b) one merged GEMM launch for all active layers
        {
            GemmArgs ga;
            for (int l = 0; l < 3; ++l) {
                GemmLayer& G = ga.L[l];
                int c = p - l;
                if (c < 0 || c >= NCH_) {
                    G.active = 0; G.K = 32;
                    G.Ahi = G.Alo = G.Bhi = G.Blo = nullptr; G.C = nullptr;
                    continue;
                }
                G.active = 1;
                if (l == 0) {
                    G.Ahi = xs_hi; G.Alo = xs_lo;
                    G.Bhi = wih0_hi; G.Blo = wih0_lo;
                    G.C = xg[0]; G.K = EP_;
                } else {
                    int slot = c & 1;
                    G.Ahi = yr_hi[l - 1] + (size_t)slot * YCH;
                    G.Alo = yr_lo[l - 1] + (size_t)slot * YCH;
                    G.Bhi = wihr_hi + (size_t)(l - 1) * SZW_;
                    G.Blo = wihr_lo + (size_t)(l - 1) * SZW_;
                    G.C = xg[l]; G.K = H_;
                }
            }
            k_gemm_multi<<<dim3(MCH_ / 128, G4_ / 128, 3), 256, 0, stream>>>(ga);
        }

        // (c) CH_ merged step launches; step i does all active layers' timesteps
        for (int i = 0; i < CH_; ++i) {
            StepArgs sa;
            for (int l = 0; l < 3; ++l) {
                LayerStep& L = sa.L[l];
                int c = p - l;
                if (c < 0 || c >= NCH_) { L.active = 0; L.t = 0;
                    L.hr = nullptr; L.hw = nullptr; L.Whi = nullptr; L.Wlo = nullptr;
                    L.xg = nullptr; L.bih = nullptr; L.bhh = nullptr; L.cbuf = nullptr;
                    L.out_t = nullptr; L.yhi = nullptr; L.ylo = nullptr; continue; }
                int t = c * CH_ + i;
                L.active = 1; L.t = t;
                L.hr   = hst[l] + (size_t)((t & 1) ^ 1) * HSTP;
                L.hw   = hst[l] + (size_t)(t & 1) * HSTP;
                L.Whi  = whh_hi + (size_t)l * SZW_;
                L.Wlo  = whh_lo + (size_t)l * SZW_;
                L.xg   = xg[l] + (size_t)i * B_ * G4_;
                L.bih  = bihA[l]; L.bhh = bhhA[l];
                L.cbuf = cbuf[l];
                L.out_t = out + (size_t)l * SB_ * H_ + (size_t)t * B_ * H_;
                if (l < 2) {
                    int slot = c & 1;
                    L.yhi = yr_hi[l] + (size_t)slot * YCH + (size_t)i * B_ * H_;
                    L.ylo = yr_lo[l] + (size_t)slot * YCH + (size_t)i * B_ * H_;
                } else { L.yhi = nullptr; L.ylo = nullptr; }
            }
            k_step_merged<<<dim3(72, 3), 256, 0, stream>>>(sa);
        }
    }
}